// Round 8
// baseline (300.212 us; speedup 1.0000x reference)
//
#include <hip/hip_runtime.h>
#include <hip/hip_bf16.h>
#include <hip/hip_fp16.h>
#include <stdint.h>
#include <stddef.h>
#include <string.h>

#define D_EMB 1024
#define SEQ   2048
#define BATCH 4

typedef short bf16x8  __attribute__((ext_vector_type(8)));
typedef short short8  __attribute__((ext_vector_type(8)));
typedef float f32x4   __attribute__((ext_vector_type(4)));

#define AS1 __attribute__((address_space(1)))
#define AS3 __attribute__((address_space(3)))

static __device__ __forceinline__ void async_copy16(const void* g, void* l) {
  __builtin_amdgcn_global_load_lds((const AS1 void*)g, (AS3 void*)l, 16, 0, 0);
}

// C[128x128] tile = A[128 x K] (row-major, lda) * Bt[128 x K]^T (Bt row-major, ldb).
// Block = 256 threads = 4 waves in 2x2; each wave does 64x64 as 4x4 MFMA 16x16x32 bf16.
// BK=64, XOR-swizzled LDS (chunk c of row r at physical chunk c^(r&7)) -> 0 bank conflicts.
// 2-stage double buffer (64 KB LDS): loads for iter i+1 issue right after the barrier,
// giving them a full 32-MFMA compute phase before the next barrier's vmcnt(0) drain.
// [R6 evidence: BK=32 dbuf (more barriers, shorter drain cover) regressed 74.8->77.8 us.]
static __device__ __forceinline__ void gemm128(
    const __hip_bfloat16* __restrict__ A, int lda,
    const __hip_bfloat16* __restrict__ Bt, int ldb,
    int K, f32x4 (&acc)[4][4])
{
  __shared__ __hip_bfloat16 ldsA[2][128 * 64];
  __shared__ __hip_bfloat16 ldsB[2][128 * 64];

  const int t    = threadIdx.x;   // 0..255
  const int wave = t >> 6;
  const int lane = t & 63;
  const int quad = lane >> 4;
  const int lr   = lane & 15;
  const int wr   = wave >> 1;
  const int wc   = wave & 1;

  // staging: 4 chunks of 4 KB per tile; chunk ch covers rows 32ch..32ch+31.
  // thread t's LDS slot is physical chunk (t&7) of row (t>>3); source col is swizzled.
  const int r0 = t >> 3;                         // 0..31
  const int c0 = (((t & 7) ^ (r0 & 7)) * 8);     // swizzled source column

  const __hip_bfloat16* gA = A  + (size_t)r0 * lda + c0;
  const __hip_bfloat16* gB = Bt + (size_t)r0 * ldb + c0;

  // hoisted swizzled read offsets for kk=0 and kk=32 (loop-invariant)
  const int pc0 = ((0 + quad) ^ (lr & 7)) * 8;
  const int pc1 = ((4 + quad) ^ (lr & 7)) * 8;
  const int arow = (wr * 64 + lr) * 64;   // + i*16*64
  const int brow = (wc * 64 + lr) * 64;   // + j*16*64

  const int niter = K >> 6;

  // prologue: stage k0=0 into buffer 0
  {
    char* lA = (char*)ldsA[0] + wave * 1024;
    char* lB = (char*)ldsB[0] + wave * 1024;
#pragma unroll
    for (int ch = 0; ch < 4; ch++) {
      async_copy16(gA + (size_t)(32 * ch) * lda, lA + 4096 * ch);
      async_copy16(gB + (size_t)(32 * ch) * ldb, lB + 4096 * ch);
    }
  }

  int buf = 0;
  for (int it = 0; it < niter; ++it) {
    __syncthreads();  // drains loads(it) [issued last iter] + prev ds_reads

    if (it + 1 < niter) {   // issue next tile's loads into the other buffer
      const int k0 = (it + 1) << 6;
      char* lA = (char*)ldsA[buf ^ 1] + wave * 1024;
      char* lB = (char*)ldsB[buf ^ 1] + wave * 1024;
#pragma unroll
      for (int ch = 0; ch < 4; ch++) {
        async_copy16(gA + k0 + (size_t)(32 * ch) * lda, lA + 4096 * ch);
        async_copy16(gB + k0 + (size_t)(32 * ch) * ldb, lB + 4096 * ch);
      }
    }

    const __hip_bfloat16* bA = ldsA[buf];
    const __hip_bfloat16* bB = ldsB[buf];
#pragma unroll
    for (int kk = 0; kk < 2; kk++) {
      const int pc = kk ? pc1 : pc0;
      bf16x8 aF[4], bF[4];
#pragma unroll
      for (int i = 0; i < 4; i++)
        aF[i] = *(const bf16x8*)&bA[arow + i * 1024 + pc];
#pragma unroll
      for (int j = 0; j < 4; j++)
        bF[j] = *(const bf16x8*)&bB[brow + j * 1024 + pc];

#pragma unroll
      for (int i = 0; i < 4; i++)
#pragma unroll
        for (int j = 0; j < 4; j++)
          acc[i][j] = __builtin_amdgcn_mfma_f32_16x16x32_bf16(aF[i], bF[j], acc[i][j], 0, 0, 0);
    }
    buf ^= 1;
  }
}

#define ZERO_ACC(acc)                         \
  {                                           \
    f32x4 _z = {0.f, 0.f, 0.f, 0.f};          \
    _Pragma("unroll")                         \
    for (int _i = 0; _i < 4; _i++)            \
      _Pragma("unroll")                       \
      for (int _j = 0; _j < 4; _j++)          \
        acc[_i][_j] = _z;                     \
  }

// ---------------- fused prep: z<3 -> transpose+cast W; z==3 -> cast x ----------------
__global__ __launch_bounds__(256) void prep_kernel(
    const float* __restrict__ x,
    const float* __restrict__ Wq,
    const float* __restrict__ Wk,
    const float* __restrict__ Wv,
    __hip_bfloat16* __restrict__ xb,
    __hip_bfloat16* __restrict__ Wt3)
{
  const int tx = threadIdx.x, ty = threadIdx.y;  // (32,8)
  if (blockIdx.z == 3) {
    const int tid = ty * 32 + tx;
    const size_t base = ((size_t)blockIdx.y * 32 + blockIdx.x) * 8192;
#pragma unroll
    for (int p = 0; p < 8; p++) {
      const size_t i = base + p * 1024 + tid * 4;
      const float4 v = *(const float4*)(x + i);
      __hip_bfloat16 o[4] = {__float2bfloat16(v.x), __float2bfloat16(v.y),
                             __float2bfloat16(v.z), __float2bfloat16(v.w)};
      *(uint64_t*)(xb + i) = *(uint64_t*)o;
    }
    return;
  }
  const float* src = (blockIdx.z == 0) ? Wq : (blockIdx.z == 1) ? Wk : Wv;
  __hip_bfloat16* dst = Wt3 + (size_t)blockIdx.z * D_EMB * D_EMB;
  __shared__ __hip_bfloat16 tile[32][33];
  const int x0 = blockIdx.x * 32;  // e
  const int y0 = blockIdx.y * 32;  // d
#pragma unroll
  for (int i = 0; i < 32; i += 8)
    tile[ty + i][tx] = __float2bfloat16(src[(size_t)(y0 + ty + i) * D_EMB + (x0 + tx)]);
  __syncthreads();
#pragma unroll
  for (int i = 0; i < 32; i += 8)
    dst[(size_t)(x0 + ty + i) * D_EMB + (y0 + tx)] = tile[tx][ty + i];
}

// ---------------- QKV projections ----------------
// grid (64 m-tiles, 8 n-tiles, 3 mats), m fastest: consecutive blocks share the
// weight B-tile (2 MB/mat fits per-XCD L2) and stream x through L3.
// z=0: Q[b][s][e], z=1: K[b][s][e], z=2: V transposed -> Vt[b][e][s]
__global__ __launch_bounds__(256) void qkv_kernel(
    const __hip_bfloat16* __restrict__ xb,
    const __hip_bfloat16* __restrict__ Wt3,
    const float* __restrict__ bq,
    const float* __restrict__ bk,
    const float* __restrict__ bv,
    __hip_bfloat16* __restrict__ Q,
    __hip_bfloat16* __restrict__ Kb,
    __hip_bfloat16* __restrict__ Vt)
{
  const int mat = blockIdx.z;
  const int m0  = blockIdx.x * 128;   // row in [0, 8192)
  const int n0  = blockIdx.y * 128;   // output dim e

  f32x4 acc[4][4];
  ZERO_ACC(acc);

  gemm128(xb + (size_t)m0 * D_EMB, D_EMB,
          Wt3 + (size_t)mat * D_EMB * D_EMB + (size_t)n0 * D_EMB, D_EMB,
          D_EMB, acc);

  const float* bias = (mat == 0) ? bq : (mat == 1) ? bk : bv;

  const int t = threadIdx.x;
  const int wave = t >> 6, lane = t & 63;
  const int quad = lane >> 4, lr = lane & 15;
  const int wr = wave >> 1, wc = wave & 1;

#pragma unroll
  for (int i = 0; i < 4; i++) {
#pragma unroll
    for (int j = 0; j < 4; j++) {
      const int n = n0 + wc * 64 + j * 16 + lr;
      const float bb = bias[n];
      const int mbase = m0 + wr * 64 + i * 16 + quad * 4;
      if (mat == 2) {
        // Vt[b][n][s], s = mbase..mbase+3 contiguous -> one 8B store
        const int b = mbase >> 11, s = mbase & 2047;
        __hip_bfloat16 pk[4];
#pragma unroll
        for (int r = 0; r < 4; r++) pk[r] = __float2bfloat16(acc[i][j][r] + bb);
        *(uint64_t*)&Vt[(size_t)b * D_EMB * SEQ + (size_t)n * SEQ + s] = *(uint64_t*)pk;
      } else {
        __hip_bfloat16* dst = (mat == 0) ? Q : Kb;
#pragma unroll
        for (int r = 0; r < 4; r++)
          dst[(size_t)(mbase + r) * D_EMB + n] = __float2bfloat16(acc[i][j][r] + bb);
      }
    }
  }
}

// ---------------- scores = Q @ K^T * scale (fp16 out) ----------------
__global__ __launch_bounds__(256) void scores_kernel(
    const __hip_bfloat16* __restrict__ Q,
    const __hip_bfloat16* __restrict__ Kb,
    __half* __restrict__ Sc)
{
  const int b  = blockIdx.z;
  const int m0 = blockIdx.y * 128;  // s_q
  const int n0 = blockIdx.x * 128;  // s_k

  f32x4 acc[4][4];
  ZERO_ACC(acc);

  gemm128(Q  + (size_t)b * SEQ * D_EMB + (size_t)m0 * D_EMB, D_EMB,
          Kb + (size_t)b * SEQ * D_EMB + (size_t)n0 * D_EMB, D_EMB,
          D_EMB, acc);

  __half* out = Sc + (size_t)b * SEQ * SEQ;
  const float scale = 0.03125f;  // 1/sqrt(1024)

  const int t = threadIdx.x;
  const int wave = t >> 6, lane = t & 63;
  const int quad = lane >> 4, lr = lane & 15;
  const int wr = wave >> 1, wc = wave & 1;

#pragma unroll
  for (int i = 0; i < 4; i++)
#pragma unroll
    for (int j = 0; j < 4; j++) {
      const int n = n0 + wc * 64 + j * 16 + lr;
#pragma unroll
      for (int r = 0; r < 4; r++) {
        const int m = m0 + wr * 64 + i * 16 + quad * 4 + r;
        out[(size_t)m * SEQ + n] = __float2half(acc[i][j][r] * scale);
      }
    }
}

// ---------------- row softmax: fp16 scores -> bf16 probs (16B vectorized) ----------------
__global__ __launch_bounds__(256) void softmax_kernel(
    const __half* __restrict__ Sc, __hip_bfloat16* __restrict__ P)
{
  const int row = blockIdx.x;  // 0..8191
  const __half* src = Sc + (size_t)row * SEQ;
  const int t = threadIdx.x;
  const int wave = t >> 6, lane = t & 63;

  // thread t owns cols t*8 .. t*8+7 : one 16B load
  const short8 raw = *(const short8*)(src + t * 8);
  float v[8];
#pragma unroll
  for (int i = 0; i < 8; i++) {
    const short si = raw[i];
    __half h;
    memcpy(&h, &si, sizeof(h));
    v[i] = __half2float(h);
  }

  float m = v[0];
#pragma unroll
  for (int i = 1; i < 8; i++) m = fmaxf(m, v[i]);
#pragma unroll
  for (int o = 32; o > 0; o >>= 1) m = fmaxf(m, __shfl_xor(m, o));

  __shared__ float redm[4];
  __shared__ float reds[4];
  if (lane == 0) redm[wave] = m;
  __syncthreads();
  m = fmaxf(fmaxf(redm[0], redm[1]), fmaxf(redm[2], redm[3]));

  float e[8], s = 0.f;
#pragma unroll
  for (int i = 0; i < 8; i++) { e[i] = __expf(v[i] - m); s += e[i]; }
#pragma unroll
  for (int o = 32; o > 0; o >>= 1) s += __shfl_xor(s, o);
  if (lane == 0) reds[wave] = s;
  __syncthreads();
  s = reds[0] + reds[1] + reds[2] + reds[3];

  const float inv = 1.f / s;
  short8 outp;
#pragma unroll
  for (int i = 0; i < 8; i++) {
    const __hip_bfloat16 b = __float2bfloat16(e[i] * inv);
    short sb;
    memcpy(&sb, &b, sizeof(sb));
    outp[i] = sb;
  }
  *(short8*)(P + (size_t)row * SEQ + t * 8) = outp;  // one 16B store
}

// ---------------- out(fp32) = P @ V  (A = probs [sq][sk], Bt = Vt [e][sk]) ----------------
__global__ __launch_bounds__(256) void pv_kernel(
    const __hip_bfloat16* __restrict__ P,
    const __hip_bfloat16* __restrict__ Vt,
    float* __restrict__ out)
{
  const int b  = blockIdx.z;
  const int m0 = blockIdx.y * 128;  // s_q
  const int n0 = blockIdx.x * 128;  // e

  f32x4 acc[4][4];
  ZERO_ACC(acc);

  gemm128(P  + (size_t)b * SEQ * SEQ   + (size_t)m0 * SEQ, SEQ,
          Vt + (size_t)b * D_EMB * SEQ + (size_t)n0 * SEQ, SEQ,
          SEQ, acc);

  float* o = out + (size_t)b * SEQ * D_EMB;

  const int t = threadIdx.x;
  const int wave = t >> 6, lane = t & 63;
  const int quad = lane >> 4, lr = lane & 15;
  const int wr = wave >> 1, wc = wave & 1;

#pragma unroll
  for (int i = 0; i < 4; i++)
#pragma unroll
    for (int j = 0; j < 4; j++) {
      const int n = n0 + wc * 64 + j * 16 + lr;
#pragma unroll
      for (int r = 0; r < 4; r++) {
        const int m = m0 + wr * 64 + i * 16 + quad * 4 + r;
        o[(size_t)m * D_EMB + n] = acc[i][j][r];
      }
    }
}

extern "C" void kernel_launch(void* const* d_in, const int* in_sizes, int n_in,
                              void* d_out, int out_size, void* d_ws, size_t ws_size,
                              hipStream_t stream) {
  const float* x  = (const float*)d_in[0];
  const float* Wq = (const float*)d_in[1];
  const float* bq = (const float*)d_in[2];
  const float* Wk = (const float*)d_in[3];
  const float* bk = (const float*)d_in[4];
  const float* Wv = (const float*)d_in[5];
  const float* bv = (const float*)d_in[6];
  float* out = (float*)d_out;

  char* ws = (char*)d_ws;
  __hip_bfloat16* xb  = (__hip_bfloat16*)(ws);
  __hip_bfloat16* Wt3 = (__hip_bfloat16*)(ws + 16777216);
  __hip_bfloat16* Q   = (__hip_bfloat16*)(ws + 23068672);
  __hip_bfloat16* Kb  = (__hip_bfloat16*)(ws + 39845888);
  __hip_bfloat16* Vt  = (__hip_bfloat16*)(ws + 56623104);
  __half*         Sc  = (__half*)        (ws + 73400320);   // 32 MB fp16
  __hip_bfloat16* P   = (__hip_bfloat16*)(ws + 140509184);
  // total = 140509184 + 33554432 = 174,063,616 bytes (~166 MB)

  prep_kernel  <<<dim3(32, 32, 4), dim3(32, 8), 0, stream>>>(x, Wq, Wk, Wv, xb, Wt3);
  qkv_kernel   <<<dim3(64, 8, 3),  256,        0, stream>>>(xb, Wt3, bq, bk, bv, Q, Kb, Vt);
  scores_kernel<<<dim3(16, 16, 4), 256,        0, stream>>>(Q, Kb, Sc);
  softmax_kernel<<<dim3(8192),     256,        0, stream>>>(Sc, P);
  pv_kernel    <<<dim3(8, 16, 4),  256,        0, stream>>>(P, Vt, out);
}

// Round 9
// 267.599 us; speedup vs baseline: 1.1219x; 1.1219x over previous
//
#include <hip/hip_runtime.h>
#include <hip/hip_bf16.h>
#include <hip/hip_fp16.h>
#include <stdint.h>
#include <stddef.h>
#include <string.h>

#define D_EMB 1024
#define SEQ   2048
#define BATCH 4

typedef short bf16x8  __attribute__((ext_vector_type(8)));
typedef short short8  __attribute__((ext_vector_type(8)));
typedef float f32x4   __attribute__((ext_vector_type(4)));

#define AS1 __attribute__((address_space(1)))
#define AS3 __attribute__((address_space(3)))

static __device__ __forceinline__ void async_copy16(const void* g, void* l) {
  __builtin_amdgcn_global_load_lds((const AS1 void*)g, (AS3 void*)l, 16, 0, 0);
}

// C[128x128] tile = A[128 x K] (row-major, lda) * Bt[128 x K]^T (Bt row-major, ldb).
// Block = 256 threads = 4 waves in 2x2; each wave does 64x64 as 4x4 MFMA 16x16x32 bf16.
// BK=64, XOR-swizzled LDS (chunk c of row r at physical chunk c^(r&7)) -> 0 bank conflicts.
// 2-stage double buffer (64 KB LDS), one barrier/iter.
// NOTE: this is the R5-verbatim body (269.3 us total, qkv 74.8 us). R7's "hoisted
// offsets + branchless pc" variant regressed qkv to 84 us (MfmaUtil 28->24.5) —
// do NOT re-hoist; the compiler's schedule here is fragile and this form wins.
static __device__ __forceinline__ void gemm128(
    const __hip_bfloat16* __restrict__ A, int lda,
    const __hip_bfloat16* __restrict__ Bt, int ldb,
    int K, f32x4 (&acc)[4][4])
{
  __shared__ __hip_bfloat16 ldsA[2][128 * 64];
  __shared__ __hip_bfloat16 ldsB[2][128 * 64];

  const int t    = threadIdx.x;   // 0..255
  const int wave = t >> 6;
  const int lane = t & 63;
  const int quad = lane >> 4;
  const int lr   = lane & 15;
  const int wr   = wave >> 1;
  const int wc   = wave & 1;

  // staging: 4 chunks of 4 KB per tile; chunk ch covers rows 32ch..32ch+31.
  // thread t's LDS slot is physical chunk (t&7) of row (t>>3); source col is swizzled.
  const int r0 = t >> 3;                         // 0..31
  const int c0 = (((t & 7) ^ (r0 & 7)) * 8);     // swizzled source column

  const __hip_bfloat16* gA = A  + (size_t)r0 * lda + c0;
  const __hip_bfloat16* gB = Bt + (size_t)r0 * ldb + c0;

  const int niter = K >> 6;

  // prologue: stage k0=0 into buffer 0
  {
    char* lA = (char*)ldsA[0] + wave * 1024;
    char* lB = (char*)ldsB[0] + wave * 1024;
#pragma unroll
    for (int ch = 0; ch < 4; ch++) {
      async_copy16(gA + (size_t)(32 * ch) * lda, lA + 4096 * ch);
      async_copy16(gB + (size_t)(32 * ch) * ldb, lB + 4096 * ch);
    }
  }

  int buf = 0;
  for (int it = 0; it < niter; ++it) {
    __syncthreads();  // drains loads(it) [issued last iter] + prev ds_reads

    if (it + 1 < niter) {   // issue next tile's loads into the other buffer
      const int k0 = (it + 1) << 6;
      char* lA = (char*)ldsA[buf ^ 1] + wave * 1024;
      char* lB = (char*)ldsB[buf ^ 1] + wave * 1024;
#pragma unroll
      for (int ch = 0; ch < 4; ch++) {
        async_copy16(gA + k0 + (size_t)(32 * ch) * lda, lA + 4096 * ch);
        async_copy16(gB + k0 + (size_t)(32 * ch) * ldb, lB + 4096 * ch);
      }
    }

    const __hip_bfloat16* bA = ldsA[buf];
    const __hip_bfloat16* bB = ldsB[buf];
#pragma unroll
    for (int kk = 0; kk < 64; kk += 32) {
      bf16x8 aF[4], bF[4];
      const int lc = (kk >> 3) + quad;           // logical chunk 0..7
      const int pc = (lc ^ (lr & 7)) * 8;        // physical element offset
#pragma unroll
      for (int i = 0; i < 4; i++)
        aF[i] = *(const bf16x8*)&bA[(wr * 64 + i * 16 + lr) * 64 + pc];
#pragma unroll
      for (int j = 0; j < 4; j++)
        bF[j] = *(const bf16x8*)&bB[(wc * 64 + j * 16 + lr) * 64 + pc];

#pragma unroll
      for (int i = 0; i < 4; i++)
#pragma unroll
        for (int j = 0; j < 4; j++)
          acc[i][j] = __builtin_amdgcn_mfma_f32_16x16x32_bf16(aF[i], bF[j], acc[i][j], 0, 0, 0);
    }
    buf ^= 1;
  }
}

#define ZERO_ACC(acc)                         \
  {                                           \
    f32x4 _z = {0.f, 0.f, 0.f, 0.f};          \
    _Pragma("unroll")                         \
    for (int _i = 0; _i < 4; _i++)            \
      _Pragma("unroll")                       \
      for (int _j = 0; _j < 4; _j++)          \
        acc[_i][_j] = _z;                     \
  }

// ---------------- fused prep: z<3 -> transpose+cast W; z==3 -> cast x ----------------
__global__ __launch_bounds__(256) void prep_kernel(
    const float* __restrict__ x,
    const float* __restrict__ Wq,
    const float* __restrict__ Wk,
    const float* __restrict__ Wv,
    __hip_bfloat16* __restrict__ xb,
    __hip_bfloat16* __restrict__ Wt3)
{
  const int tx = threadIdx.x, ty = threadIdx.y;  // (32,8)
  if (blockIdx.z == 3) {
    const int tid = ty * 32 + tx;
    const size_t base = ((size_t)blockIdx.y * 32 + blockIdx.x) * 8192;
#pragma unroll
    for (int p = 0; p < 8; p++) {
      const size_t i = base + p * 1024 + tid * 4;
      const float4 v = *(const float4*)(x + i);
      __hip_bfloat16 o[4] = {__float2bfloat16(v.x), __float2bfloat16(v.y),
                             __float2bfloat16(v.z), __float2bfloat16(v.w)};
      *(uint64_t*)(xb + i) = *(uint64_t*)o;
    }
    return;
  }
  const float* src = (blockIdx.z == 0) ? Wq : (blockIdx.z == 1) ? Wk : Wv;
  __hip_bfloat16* dst = Wt3 + (size_t)blockIdx.z * D_EMB * D_EMB;
  __shared__ __hip_bfloat16 tile[32][33];
  const int x0 = blockIdx.x * 32;  // e
  const int y0 = blockIdx.y * 32;  // d
#pragma unroll
  for (int i = 0; i < 32; i += 8)
    tile[ty + i][tx] = __float2bfloat16(src[(size_t)(y0 + ty + i) * D_EMB + (x0 + tx)]);
  __syncthreads();
#pragma unroll
  for (int i = 0; i < 32; i += 8)
    dst[(size_t)(x0 + ty + i) * D_EMB + (y0 + tx)] = tile[tx][ty + i];
}

// ---------------- QKV projections ----------------
// grid (64 m-tiles, 8 n-tiles, 3 mats), m fastest: consecutive blocks share the
// weight B-tile (2 MB/mat fits per-XCD L2) and stream x through L3.
// z=0: Q[b][s][e], z=1: K[b][s][e], z=2: V transposed -> Vt[b][e][s]
__global__ __launch_bounds__(256) void qkv_kernel(
    const __hip_bfloat16* __restrict__ xb,
    const __hip_bfloat16* __restrict__ Wt3,
    const float* __restrict__ bq,
    const float* __restrict__ bk,
    const float* __restrict__ bv,
    __hip_bfloat16* __restrict__ Q,
    __hip_bfloat16* __restrict__ Kb,
    __hip_bfloat16* __restrict__ Vt)
{
  const int mat = blockIdx.z;
  const int m0  = blockIdx.x * 128;   // row in [0, 8192)
  const int n0  = blockIdx.y * 128;   // output dim e

  f32x4 acc[4][4];
  ZERO_ACC(acc);

  gemm128(xb + (size_t)m0 * D_EMB, D_EMB,
          Wt3 + (size_t)mat * D_EMB * D_EMB + (size_t)n0 * D_EMB, D_EMB,
          D_EMB, acc);

  const float* bias = (mat == 0) ? bq : (mat == 1) ? bk : bv;

  const int t = threadIdx.x;
  const int wave = t >> 6, lane = t & 63;
  const int quad = lane >> 4, lr = lane & 15;
  const int wr = wave >> 1, wc = wave & 1;

#pragma unroll
  for (int i = 0; i < 4; i++) {
#pragma unroll
    for (int j = 0; j < 4; j++) {
      const int n = n0 + wc * 64 + j * 16 + lr;
      const float bb = bias[n];
      const int mbase = m0 + wr * 64 + i * 16 + quad * 4;
      if (mat == 2) {
        // Vt[b][n][s], s = mbase..mbase+3 contiguous -> one 8B store
        const int b = mbase >> 11, s = mbase & 2047;
        __hip_bfloat16 pk[4];
#pragma unroll
        for (int r = 0; r < 4; r++) pk[r] = __float2bfloat16(acc[i][j][r] + bb);
        *(uint64_t*)&Vt[(size_t)b * D_EMB * SEQ + (size_t)n * SEQ + s] = *(uint64_t*)pk;
      } else {
        __hip_bfloat16* dst = (mat == 0) ? Q : Kb;
#pragma unroll
        for (int r = 0; r < 4; r++)
          dst[(size_t)(mbase + r) * D_EMB + n] = __float2bfloat16(acc[i][j][r] + bb);
      }
    }
  }
}

// ---------------- scores = Q @ K^T * scale (fp16 out) ----------------
__global__ __launch_bounds__(256) void scores_kernel(
    const __hip_bfloat16* __restrict__ Q,
    const __hip_bfloat16* __restrict__ Kb,
    __half* __restrict__ Sc)
{
  const int b  = blockIdx.z;
  const int m0 = blockIdx.y * 128;  // s_q
  const int n0 = blockIdx.x * 128;  // s_k

  f32x4 acc[4][4];
  ZERO_ACC(acc);

  gemm128(Q  + (size_t)b * SEQ * D_EMB + (size_t)m0 * D_EMB, D_EMB,
          Kb + (size_t)b * SEQ * D_EMB + (size_t)n0 * D_EMB, D_EMB,
          D_EMB, acc);

  __half* out = Sc + (size_t)b * SEQ * SEQ;
  const float scale = 0.03125f;  // 1/sqrt(1024)

  const int t = threadIdx.x;
  const int wave = t >> 6, lane = t & 63;
  const int quad = lane >> 4, lr = lane & 15;
  const int wr = wave >> 1, wc = wave & 1;

#pragma unroll
  for (int i = 0; i < 4; i++)
#pragma unroll
    for (int j = 0; j < 4; j++) {
      const int n = n0 + wc * 64 + j * 16 + lr;
#pragma unroll
      for (int r = 0; r < 4; r++) {
        const int m = m0 + wr * 64 + i * 16 + quad * 4 + r;
        out[(size_t)m * SEQ + n] = __float2half(acc[i][j][r] * scale);
      }
    }
}

// ---------------- row softmax: fp16 scores -> bf16 probs (16B vectorized) ----------------
__global__ __launch_bounds__(256) void softmax_kernel(
    const __half* __restrict__ Sc, __hip_bfloat16* __restrict__ P)
{
  const int row = blockIdx.x;  // 0..8191
  const __half* src = Sc + (size_t)row * SEQ;
  const int t = threadIdx.x;
  const int wave = t >> 6, lane = t & 63;

  // thread t owns cols t*8 .. t*8+7 : one 16B load
  const short8 raw = *(const short8*)(src + t * 8);
  float v[8];
#pragma unroll
  for (int i = 0; i < 8; i++) {
    const short si = raw[i];
    __half h;
    memcpy(&h, &si, sizeof(h));
    v[i] = __half2float(h);
  }

  float m = v[0];
#pragma unroll
  for (int i = 1; i < 8; i++) m = fmaxf(m, v[i]);
#pragma unroll
  for (int o = 32; o > 0; o >>= 1) m = fmaxf(m, __shfl_xor(m, o));

  __shared__ float redm[4];
  __shared__ float reds[4];
  if (lane == 0) redm[wave] = m;
  __syncthreads();
  m = fmaxf(fmaxf(redm[0], redm[1]), fmaxf(redm[2], redm[3]));

  float e[8], s = 0.f;
#pragma unroll
  for (int i = 0; i < 8; i++) { e[i] = __expf(v[i] - m); s += e[i]; }
#pragma unroll
  for (int o = 32; o > 0; o >>= 1) s += __shfl_xor(s, o);
  if (lane == 0) reds[wave] = s;
  __syncthreads();
  s = reds[0] + reds[1] + reds[2] + reds[3];

  const float inv = 1.f / s;
  short8 outp;
#pragma unroll
  for (int i = 0; i < 8; i++) {
    const __hip_bfloat16 b = __float2bfloat16(e[i] * inv);
    short sb;
    memcpy(&sb, &b, sizeof(sb));
    outp[i] = sb;
  }
  *(short8*)(P + (size_t)row * SEQ + t * 8) = outp;  // one 16B store
}

// ---------------- out(fp32) = P @ V  (A = probs [sq][sk], Bt = Vt [e][sk]) ----------------
__global__ __launch_bounds__(256) void pv_kernel(
    const __hip_bfloat16* __restrict__ P,
    const __hip_bfloat16* __restrict__ Vt,
    float* __restrict__ out)
{
  const int b  = blockIdx.z;
  const int m0 = blockIdx.y * 128;  // s_q
  const int n0 = blockIdx.x * 128;  // e

  f32x4 acc[4][4];
  ZERO_ACC(acc);

  gemm128(P  + (size_t)b * SEQ * SEQ   + (size_t)m0 * SEQ, SEQ,
          Vt + (size_t)b * D_EMB * SEQ + (size_t)n0 * SEQ, SEQ,
          SEQ, acc);

  float* o = out + (size_t)b * SEQ * D_EMB;

  const int t = threadIdx.x;
  const int wave = t >> 6, lane = t & 63;
  const int quad = lane >> 4, lr = lane & 15;
  const int wr = wave >> 1, wc = wave & 1;

#pragma unroll
  for (int i = 0; i < 4; i++)
#pragma unroll
    for (int j = 0; j < 4; j++) {
      const int n = n0 + wc * 64 + j * 16 + lr;
#pragma unroll
      for (int r = 0; r < 4; r++) {
        const int m = m0 + wr * 64 + i * 16 + quad * 4 + r;
        o[(size_t)m * D_EMB + n] = acc[i][j][r];
      }
    }
}

extern "C" void kernel_launch(void* const* d_in, const int* in_sizes, int n_in,
                              void* d_out, int out_size, void* d_ws, size_t ws_size,
                              hipStream_t stream) {
  const float* x  = (const float*)d_in[0];
  const float* Wq = (const float*)d_in[1];
  const float* bq = (const float*)d_in[2];
  const float* Wk = (const float*)d_in[3];
  const float* bk = (const float*)d_in[4];
  const float* Wv = (const float*)d_in[5];
  const float* bv = (const float*)d_in[6];
  float* out = (float*)d_out;

  char* ws = (char*)d_ws;
  __hip_bfloat16* xb  = (__hip_bfloat16*)(ws);
  __hip_bfloat16* Wt3 = (__hip_bfloat16*)(ws + 16777216);
  __hip_bfloat16* Q   = (__hip_bfloat16*)(ws + 23068672);
  __hip_bfloat16* Kb  = (__hip_bfloat16*)(ws + 39845888);
  __hip_bfloat16* Vt  = (__hip_bfloat16*)(ws + 56623104);
  __half*         Sc  = (__half*)        (ws + 73400320);   // 32 MB fp16
  __hip_bfloat16* P   = (__hip_bfloat16*)(ws + 140509184);
  // total = 140509184 + 33554432 = 174,063,616 bytes (~166 MB)

  prep_kernel  <<<dim3(32, 32, 4), dim3(32, 8), 0, stream>>>(x, Wq, Wk, Wv, xb, Wt3);
  qkv_kernel   <<<dim3(64, 8, 3),  256,        0, stream>>>(xb, Wt3, bq, bk, bv, Q, Kb, Vt);
  scores_kernel<<<dim3(16, 16, 4), 256,        0, stream>>>(Q, Kb, Sc);
  softmax_kernel<<<dim3(8192),     256,        0, stream>>>(Sc, P);
  pv_kernel    <<<dim3(8, 16, 4),  256,        0, stream>>>(P, Vt, out);
}